// Round 7
// baseline (252.124 us; speedup 1.0000x reference)
//
#include <hip/hip_runtime.h>
#include <math.h>

#define Bq 8
#define T 512
#define D 1024
#define R 4
#define V 2048
#define NCOL (V * R * R)        // 32768 columns of w_vocab
#define DSPLIT 16
#define DCHUNK (D / DSPLIT)     // 64 d-rows per k_core block
#define CBLK 1024               // cols per k_core block (256 thr * float4)
#define NTC 32                  // t-chunks in k_xbar (16 t each)

// ---------------------------------------------------------------------------
// K0 (probe/fix): contiguous grid-stride read of all 128 MB of wv.
// Purpose: (a) if cold CONTIGUOUS reads run at ~6 TB/s this warms L3 so
// k_core's strided pass runs at the measured ~7 TB/s warm rate (R4 shadow);
// (b) if cold reads cap at ~3.2 TB/s regardless of pattern, total stays flat
// and we have the roofline answer. Reads allocate into L3 (R1/R4 FETCH
// evidence). No stores, keep-alive asm -> zero correctness risk.
// 2048 blocks x 256 thr; 16 float4/thread in two 8-deep batches.
// ---------------------------------------------------------------------------
__global__ __launch_bounds__(256, 2)
void k_pref(const float* __restrict__ wv) {
    const float4* p = (const float4*)wv;
    size_t i0   = (size_t)blockIdx.x * 256 + threadIdx.x;
    const size_t step = (size_t)2048 * 256;      // 524288 threads
    float4 a0 = make_float4(0.f, 0.f, 0.f, 0.f);
    float4 a1 = a0, a2 = a0, a3 = a0;
#pragma unroll
    for (int u = 0; u < 16; ++u) {
        float4 v = p[i0 + (size_t)u * step];     // 16 independent loads
        if ((u & 3) == 0) { a0.x += v.x; a0.y += v.y; a0.z += v.z; a0.w += v.w; }
        else if ((u & 3) == 1) { a1.x += v.x; a1.y += v.y; a1.z += v.z; a1.w += v.w; }
        else if ((u & 3) == 2) { a2.x += v.x; a2.y += v.y; a2.z += v.z; a2.w += v.w; }
        else { a3.x += v.x; a3.y += v.y; a3.z += v.z; a3.w += v.w; }
    }
    float sx = a0.x + a1.x + a2.x + a3.x;
    float sy = a0.y + a1.y + a2.y + a3.y;
    float sz = a0.z + a1.z + a2.z + a3.z;
    float sw = a0.w + a1.w + a2.w + a3.w;
    asm volatile("" :: "v"(sx), "v"(sy), "v"(sz), "v"(sw));
}

// ---------------------------------------------------------------------------
// K1: partial[b][tc][d] = sum of 16 t's of x[b][.][d].
// ---------------------------------------------------------------------------
__global__ void k_xbar(const float* __restrict__ x, float* __restrict__ partial,
                       float* __restrict__ out) {
    int b   = blockIdx.x;
    int tc  = blockIdx.y;
    int tid = threadIdx.x;
    if (b == 0 && tc == 0 && tid == 0) out[0] = 0.f;
    const float4* xp = (const float4*)(x + ((size_t)b * T + (size_t)tc * 16) * D) + tid;
    float4 acc = make_float4(0.f, 0.f, 0.f, 0.f);
#pragma unroll
    for (int t = 0; t < 16; ++t) {
        float4 v = xp[t * (D / 4)];
        acc.x += v.x; acc.y += v.y; acc.z += v.z; acc.w += v.w;
    }
    *(float4*)(partial + ((size_t)b * NTC + tc) * D + tid * 4) = acc;
}

// ---------------------------------------------------------------------------
// K1b: xbar[b][d] = sum over 32 tc of partial (ascending tc -> bit-exact).
// ---------------------------------------------------------------------------
__global__ void k_xred(const float* __restrict__ partial, float* __restrict__ xbar) {
    int q  = blockIdx.x * 256 + threadIdx.x;   // 0..8191
    int b  = q >> 10;
    int dd = q & 1023;
    const float* pp = partial + (size_t)b * NTC * D + dd;
    float s = 0.f;
#pragma unroll
    for (int tc = 0; tc < NTC; ++tc) s += pp[(size_t)tc * D];
    xbar[q] = s;
}

// ---------------------------------------------------------------------------
// K2: part[ds][b][col] = sum_{d in chunk ds} xbar[b][d] * w_vocab[d][col]
// Exact R2 version (232.8 baseline). R6 showed deeper MLP doesn't help;
// with k_pref ahead, this reads L3-warm wv (~7 TB/s measured warm rate).
// ---------------------------------------------------------------------------
__global__ void k_core(const float* __restrict__ wv, const float* __restrict__ xbar,
                       float* __restrict__ part) {
    __shared__ float xs[Bq * DCHUNK];  // 8 x 64 floats = 2 KB
    int tid  = threadIdx.x;            // 0..255
    int colb = blockIdx.x;             // 0..31
    int ds   = blockIdx.y;             // 0..15
    int d0   = ds * DCHUNK;

    if (tid < 128) {
        int q4 = tid * 4;
        int b  = q4 >> 6;
        int dd = q4 & 63;
        *(float4*)(xs + q4) = *(const float4*)(xbar + b * D + d0 + dd);
    }
    __syncthreads();

    int col = colb * CBLK + tid * 4;
    const float4* wp = (const float4*)(wv + (size_t)d0 * NCOL + col);
    float4 acc[Bq];
#pragma unroll
    for (int b = 0; b < Bq; ++b) acc[b] = make_float4(0.f, 0.f, 0.f, 0.f);

#pragma unroll 8
    for (int d = 0; d < DCHUNK; ++d) {
        float4 w = wp[(size_t)d * (NCOL / 4)];
#pragma unroll
        for (int b = 0; b < Bq; ++b) {
            float xv = xs[b * DCHUNK + d];
            acc[b].x += w.x * xv;
            acc[b].y += w.y * xv;
            acc[b].z += w.z * xv;
            acc[b].w += w.w * xv;
        }
    }

#pragma unroll
    for (int b = 0; b < Bq; ++b)
        *(float4*)(part + ((size_t)ds * Bq + b) * NCOL + col) = acc[b];
}

// ---------------------------------------------------------------------------
// K3: gather + column-normalize + per-block chunk product. (R2 code, exact)
// ---------------------------------------------------------------------------
__global__ void k_gather(const float* __restrict__ part, const int* __restrict__ labels,
                         float* __restrict__ bprod) {
    __shared__ float Mn_s[64 * 16];   // 4 KB: this block's 64 matrices
    __shared__ float gm[8][17];       // chunk products, +1 pad
    int b   = blockIdx.x;
    int tc  = blockIdx.y;
    int tid = threadIdx.x;
    int tl  = tid >> 2;               // 0..63 local t
    int i   = tid & 3;                // matrix row
    int t   = tc * 64 + tl;
    int y   = labels[b * T + t];

    const float* pb = part + (size_t)b * NCOL + (size_t)i * (V * R) + (size_t)y * R;
    float4 g = make_float4(0.f, 0.f, 0.f, 0.f);
#pragma unroll
    for (int ds = 0; ds < DSPLIT; ++ds) {
        float4 v = *(const float4*)(pb + (size_t)ds * (Bq * NCOL));
        g.x += v.x; g.y += v.y; g.z += v.z; g.w += v.w;
    }
    g.x = fabsf(g.x); g.y = fabsf(g.y); g.z = fabsf(g.z); g.w = fabsf(g.w);

    float sx = g.x, sy = g.y, sz = g.z, sw = g.w;
    sx += __shfl_xor(sx, 1); sy += __shfl_xor(sy, 1);
    sz += __shfl_xor(sz, 1); sw += __shfl_xor(sw, 1);
    sx += __shfl_xor(sx, 2); sy += __shfl_xor(sy, 2);
    sz += __shfl_xor(sz, 2); sw += __shfl_xor(sw, 2);

    float4 o = make_float4(g.x / sx, g.y / sy, g.z / sz, g.w / sw);
    *(float4*)(Mn_s + tl * 16 + i * 4) = o;
    __syncthreads();

    int c = tid;
    if (c < 8) {
        const float* mp = Mn_s + c * 8 * 16;
        float P[R][R];
        {
            float4 m0 = *(const float4*)(mp + 0);
            float4 m1 = *(const float4*)(mp + 4);
            float4 m2 = *(const float4*)(mp + 8);
            float4 m3 = *(const float4*)(mp + 12);
            P[0][0]=m0.x; P[0][1]=m0.y; P[0][2]=m0.z; P[0][3]=m0.w;
            P[1][0]=m1.x; P[1][1]=m1.y; P[1][2]=m1.z; P[1][3]=m1.w;
            P[2][0]=m2.x; P[2][1]=m2.y; P[2][2]=m2.z; P[2][3]=m2.w;
            P[3][0]=m3.x; P[3][1]=m3.y; P[3][2]=m3.z; P[3][3]=m3.w;
        }
#pragma unroll
        for (int k = 1; k < 8; ++k) {
            float4 m0 = *(const float4*)(mp + k * 16 + 0);
            float4 m1 = *(const float4*)(mp + k * 16 + 4);
            float4 m2 = *(const float4*)(mp + k * 16 + 8);
            float4 m3 = *(const float4*)(mp + k * 16 + 12);
            float M[R][R] = {{m0.x, m0.y, m0.z, m0.w},
                             {m1.x, m1.y, m1.z, m1.w},
                             {m2.x, m2.y, m2.z, m2.w},
                             {m3.x, m3.y, m3.z, m3.w}};
            float N[R][R];
#pragma unroll
            for (int ii = 0; ii < R; ++ii)
#pragma unroll
                for (int j = 0; j < R; ++j)
                    N[ii][j] = M[ii][0] * P[0][j] + M[ii][1] * P[1][j] +
                               M[ii][2] * P[2][j] + M[ii][3] * P[3][j];
#pragma unroll
            for (int ii = 0; ii < R; ++ii)
#pragma unroll
                for (int j = 0; j < R; ++j) P[ii][j] = N[ii][j];
        }
#pragma unroll
        for (int ii = 0; ii < R; ++ii)
#pragma unroll
            for (int j = 0; j < R; ++j) gm[c][ii * 4 + j] = P[ii][j];
    }
    __syncthreads();

    for (int rnd = 0; rnd < 3; ++rnd) {
        int step = 1 << rnd;
        bool act = (c < 8) && ((c & (2 * step - 1)) == 0);
        float N2[R][R];
        if (act) {
            float A[R][R], Bm[R][R];
#pragma unroll
            for (int ii = 0; ii < R; ++ii)
#pragma unroll
                for (int j = 0; j < R; ++j) {
                    A[ii][j]  = gm[c + step][ii * 4 + j];
                    Bm[ii][j] = gm[c][ii * 4 + j];
                }
#pragma unroll
            for (int ii = 0; ii < R; ++ii)
#pragma unroll
                for (int j = 0; j < R; ++j)
                    N2[ii][j] = A[ii][0] * Bm[0][j] + A[ii][1] * Bm[1][j] +
                                A[ii][2] * Bm[2][j] + A[ii][3] * Bm[3][j];
        }
        __syncthreads();
        if (act) {
#pragma unroll
            for (int ii = 0; ii < R; ++ii)
#pragma unroll
                for (int j = 0; j < R; ++j) gm[c][ii * 4 + j] = N2[ii][j];
        }
        __syncthreads();
    }

    if (tid < 4)
        *(float4*)(bprod + ((size_t)(b * 8 + tc)) * 16 + tid * 4) =
            *(const float4*)(&gm[0][tid * 4]);
}

// ---------------------------------------------------------------------------
// K4: one block per batch, 64 threads. (R2 code, exact)
// ---------------------------------------------------------------------------
__global__ void k_chain(const float* __restrict__ bprod, const float* __restrict__ xbar,
                        const float* __restrict__ wa, const float* __restrict__ wb,
                        float* __restrict__ out) {
    __shared__ float mats[8][17];     // +1 pad
    __shared__ float abp[64];
    int b   = blockIdx.x;
    int tid = threadIdx.x;            // 0..63

    {
        int r   = tid & 3;
        int sel = (tid >> 2) & 1;
        int seg = tid >> 3;           // 0..7, 128 d each
        const float* w  = sel ? wb : wa;
        const float* xp = xbar + b * D;
        float s = 0.f;
#pragma unroll 8
        for (int d = seg * 128; d < seg * 128 + 128; ++d)
            s += xp[d] * w[d * R + r];
        abp[tid] = s;
    }

    if (tid < 32) {
        int c = tid >> 2, q = tid & 3;
        *(float4*)(&mats[c][q * 4]) =
            *(const float4*)(bprod + ((size_t)(b * 8 + c)) * 16 + q * 4);
    }
    __syncthreads();

    int c = tid;
    for (int rnd = 0; rnd < 3; ++rnd) {
        int step = 1 << rnd;
        bool act = (c < 8) && ((c & (2 * step - 1)) == 0);
        float N2[R][R];
        if (act) {
            float A[R][R], Bm[R][R];
#pragma unroll
            for (int i = 0; i < R; ++i)
#pragma unroll
                for (int j = 0; j < R; ++j) {
                    A[i][j]  = mats[c + step][i * 4 + j];
                    Bm[i][j] = mats[c][i * 4 + j];
                }
#pragma unroll
            for (int i = 0; i < R; ++i)
#pragma unroll
                for (int j = 0; j < R; ++j)
                    N2[i][j] = A[i][0] * Bm[0][j] + A[i][1] * Bm[1][j] +
                               A[i][2] * Bm[2][j] + A[i][3] * Bm[3][j];
        }
        __syncthreads();
        if (act) {
#pragma unroll
            for (int i = 0; i < R; ++i)
#pragma unroll
                for (int j = 0; j < R; ++j) mats[c][i * 4 + j] = N2[i][j];
        }
        __syncthreads();
    }

    if (tid == 0) {
        float a[R], be[R];
#pragma unroll
        for (int r = 0; r < R; ++r) {
            float sa = 0.f, sb = 0.f;
#pragma unroll
            for (int seg = 0; seg < 8; ++seg) {
                sa += abp[(seg << 3) | r];
                sb += abp[(seg << 3) | 4 | r];
            }
            a[r] = sa; be[r] = sb;
        }
        float sa = fabsf(a[0]) + fabsf(a[1]) + fabsf(a[2]) + fabsf(a[3]);
        float v0[R];
#pragma unroll
        for (int r = 0; r < R; ++r) v0[r] = fabsf(a[r]) / sa;
        float v[R];
#pragma unroll
        for (int i = 0; i < R; ++i)
            v[i] = mats[0][i * 4 + 0] * v0[0] + mats[0][i * 4 + 1] * v0[1] +
                   mats[0][i * 4 + 2] * v0[2] + mats[0][i * 4 + 3] * v0[3];
        float sb = fabsf(be[0]) + fabsf(be[1]) + fabsf(be[2]) + fabsf(be[3]);
        float prob = (fabsf(be[0]) * v[0] + fabsf(be[1]) * v[1] +
                      fabsf(be[2]) * v[2] + fabsf(be[3]) * v[3]) / sb;
        atomicAdd(out, -logf(prob) * 0.125f);
    }
}

extern "C" void kernel_launch(void* const* d_in, const int* in_sizes, int n_in,
                              void* d_out, int out_size, void* d_ws, size_t ws_size,
                              hipStream_t stream) {
    const float* x      = (const float*)d_in[0];   // [8,512,1024] fp32
    const int*   labels = (const int*)d_in[1];     // [8,512] int32
    const float* wa     = (const float*)d_in[2];   // [1024,4]
    const float* wb     = (const float*)d_in[3];   // [1024,4]
    const float* wv     = (const float*)d_in[4];   // [1024,32768]
    float* out = (float*)d_out;                    // scalar loss

    float* xbar    = (float*)d_ws;                           // 8192 floats
    float* partial = xbar + Bq * D;                          // 8*32*1024 = 1 MiB
    float* part    = partial + (size_t)Bq * NTC * D;         // 16*8*32768 = 16 MiB
    float* bprod   = part + (size_t)DSPLIT * Bq * NCOL;      // 8*8*16 floats

    k_pref<<<2048, 256, 0, stream>>>(wv);
    k_xbar<<<dim3(Bq, NTC), 256, 0, stream>>>(x, partial, out);
    k_xred<<<32, 256, 0, stream>>>(partial, xbar);
    k_core<<<dim3(NCOL / CBLK, DSPLIT), 256, 0, stream>>>(wv, xbar, part);
    k_gather<<<dim3(Bq, 8), 256, 0, stream>>>(part, labels, bprod);
    k_chain<<<Bq, 64, 0, stream>>>(bprod, xbar, wa, wb, out);
}

// Round 8
// 225.142 us; speedup vs baseline: 1.1198x; 1.1198x over previous
//
#include <hip/hip_runtime.h>
#include <math.h>

#define Bq 8
#define T 512
#define D 1024
#define R 4
#define V 2048
#define NCOL (V * R * R)        // 32768 columns of w_vocab
#define DSPLIT 16
#define DCHUNK (D / DSPLIT)     // 64 d-rows per k_core block
#define CBLK 1024               // cols per k_core block (256 thr * float4)
#define NTC 32                  // t-chunks in k_xbar (16 t each)

typedef float vf4 __attribute__((ext_vector_type(4)));

// ---------------------------------------------------------------------------
// K1: partial[b][tc][d] = sum of 16 t's of x[b][.][d].
// x is streamed once and never re-read -> non-temporal loads (no L2/L3
// allocation, no dirty-line evictions of the harness poison fill).
// ---------------------------------------------------------------------------
__global__ void k_xbar(const float* __restrict__ x, float* __restrict__ partial,
                       float* __restrict__ out) {
    int b   = blockIdx.x;
    int tc  = blockIdx.y;
    int tid = threadIdx.x;
    if (b == 0 && tc == 0 && tid == 0) out[0] = 0.f;
    const vf4* xp = (const vf4*)(x + ((size_t)b * T + (size_t)tc * 16) * D) + tid;
    float ax = 0.f, ay = 0.f, az = 0.f, aw = 0.f;
#pragma unroll
    for (int t = 0; t < 16; ++t) {
        vf4 v = __builtin_nontemporal_load(xp + (size_t)t * (D / 4));
        ax += v[0]; ay += v[1]; az += v[2]; aw += v[3];
    }
    float4 acc = make_float4(ax, ay, az, aw);
    *(float4*)(partial + ((size_t)b * NTC + tc) * D + tid * 4) = acc;
}

// ---------------------------------------------------------------------------
// K1b: xbar[b][d] = sum over 32 tc of partial (ascending tc -> bit-exact).
// ---------------------------------------------------------------------------
__global__ void k_xred(const float* __restrict__ partial, float* __restrict__ xbar) {
    int q  = blockIdx.x * 256 + threadIdx.x;   // 0..8191
    int b  = q >> 10;
    int dd = q & 1023;
    const float* pp = partial + (size_t)b * NTC * D + dd;
    float s = 0.f;
#pragma unroll
    for (int tc = 0; tc < NTC; ++tc) s += pp[(size_t)tc * D];
    xbar[q] = s;
}

// ---------------------------------------------------------------------------
// K2: part[ds][b][col] = sum_{d in chunk ds} xbar[b][d] * w_vocab[d][col]
// Exact R2 structure (232.8 baseline); the ONLY change is non-temporal wv
// loads. Theory (R4/R6/R7 evidence): cold reads ran at 2.2-3.2 TB/s because
// every read miss had to evict a dirty L3 line left by the 512 MiB poison
// fill (writeback steals ~half the fabric). nt loads don't allocate ->
// no forced evictions -> read stream approaches the clean ~6 TB/s rate.
// Same values, same FMA order -> bit-exact.
// ---------------------------------------------------------------------------
__global__ void k_core(const float* __restrict__ wv, const float* __restrict__ xbar,
                       float* __restrict__ part) {
    __shared__ float xs[Bq * DCHUNK];  // 8 x 64 floats = 2 KB
    int tid  = threadIdx.x;            // 0..255
    int colb = blockIdx.x;             // 0..31
    int ds   = blockIdx.y;             // 0..15
    int d0   = ds * DCHUNK;

    if (tid < 128) {
        int q4 = tid * 4;
        int b  = q4 >> 6;
        int dd = q4 & 63;
        *(float4*)(xs + q4) = *(const float4*)(xbar + b * D + d0 + dd);
    }
    __syncthreads();

    int col = colb * CBLK + tid * 4;
    const vf4* wp = (const vf4*)(wv + (size_t)d0 * NCOL + col);
    float4 acc[Bq];
#pragma unroll
    for (int b = 0; b < Bq; ++b) acc[b] = make_float4(0.f, 0.f, 0.f, 0.f);

#pragma unroll 8
    for (int d = 0; d < DCHUNK; ++d) {
        vf4 w = __builtin_nontemporal_load(wp + (size_t)d * (NCOL / 4));
#pragma unroll
        for (int b = 0; b < Bq; ++b) {
            float xv = xs[b * DCHUNK + d];
            acc[b].x += w[0] * xv;
            acc[b].y += w[1] * xv;
            acc[b].z += w[2] * xv;
            acc[b].w += w[3] * xv;
        }
    }

#pragma unroll
    for (int b = 0; b < Bq; ++b)
        *(float4*)(part + ((size_t)ds * Bq + b) * NCOL + col) = acc[b];
}

// ---------------------------------------------------------------------------
// K3: gather + column-normalize + per-block chunk product. (R2 code, exact)
// ---------------------------------------------------------------------------
__global__ void k_gather(const float* __restrict__ part, const int* __restrict__ labels,
                         float* __restrict__ bprod) {
    __shared__ float Mn_s[64 * 16];   // 4 KB: this block's 64 matrices
    __shared__ float gm[8][17];       // chunk products, +1 pad
    int b   = blockIdx.x;
    int tc  = blockIdx.y;
    int tid = threadIdx.x;
    int tl  = tid >> 2;               // 0..63 local t
    int i   = tid & 3;                // matrix row
    int t   = tc * 64 + tl;
    int y   = labels[b * T + t];

    const float* pb = part + (size_t)b * NCOL + (size_t)i * (V * R) + (size_t)y * R;
    float4 g = make_float4(0.f, 0.f, 0.f, 0.f);
#pragma unroll
    for (int ds = 0; ds < DSPLIT; ++ds) {
        float4 v = *(const float4*)(pb + (size_t)ds * (Bq * NCOL));
        g.x += v.x; g.y += v.y; g.z += v.z; g.w += v.w;
    }
    g.x = fabsf(g.x); g.y = fabsf(g.y); g.z = fabsf(g.z); g.w = fabsf(g.w);

    float sx = g.x, sy = g.y, sz = g.z, sw = g.w;
    sx += __shfl_xor(sx, 1); sy += __shfl_xor(sy, 1);
    sz += __shfl_xor(sz, 1); sw += __shfl_xor(sw, 1);
    sx += __shfl_xor(sx, 2); sy += __shfl_xor(sy, 2);
    sz += __shfl_xor(sz, 2); sw += __shfl_xor(sw, 2);

    float4 o = make_float4(g.x / sx, g.y / sy, g.z / sz, g.w / sw);
    *(float4*)(Mn_s + tl * 16 + i * 4) = o;
    __syncthreads();

    int c = tid;
    if (c < 8) {
        const float* mp = Mn_s + c * 8 * 16;
        float P[R][R];
        {
            float4 m0 = *(const float4*)(mp + 0);
            float4 m1 = *(const float4*)(mp + 4);
            float4 m2 = *(const float4*)(mp + 8);
            float4 m3 = *(const float4*)(mp + 12);
            P[0][0]=m0.x; P[0][1]=m0.y; P[0][2]=m0.z; P[0][3]=m0.w;
            P[1][0]=m1.x; P[1][1]=m1.y; P[1][2]=m1.z; P[1][3]=m1.w;
            P[2][0]=m2.x; P[2][1]=m2.y; P[2][2]=m2.z; P[2][3]=m2.w;
            P[3][0]=m3.x; P[3][1]=m3.y; P[3][2]=m3.z; P[3][3]=m3.w;
        }
#pragma unroll
        for (int k = 1; k < 8; ++k) {
            float4 m0 = *(const float4*)(mp + k * 16 + 0);
            float4 m1 = *(const float4*)(mp + k * 16 + 4);
            float4 m2 = *(const float4*)(mp + k * 16 + 8);
            float4 m3 = *(const float4*)(mp + k * 16 + 12);
            float M[R][R] = {{m0.x, m0.y, m0.z, m0.w},
                             {m1.x, m1.y, m1.z, m1.w},
                             {m2.x, m2.y, m2.z, m2.w},
                             {m3.x, m3.y, m3.z, m3.w}};
            float N[R][R];
#pragma unroll
            for (int ii = 0; ii < R; ++ii)
#pragma unroll
                for (int j = 0; j < R; ++j)
                    N[ii][j] = M[ii][0] * P[0][j] + M[ii][1] * P[1][j] +
                               M[ii][2] * P[2][j] + M[ii][3] * P[3][j];
#pragma unroll
            for (int ii = 0; ii < R; ++ii)
#pragma unroll
                for (int j = 0; j < R; ++j) P[ii][j] = N[ii][j];
        }
#pragma unroll
        for (int ii = 0; ii < R; ++ii)
#pragma unroll
            for (int j = 0; j < R; ++j) gm[c][ii * 4 + j] = P[ii][j];
    }
    __syncthreads();

    for (int rnd = 0; rnd < 3; ++rnd) {
        int step = 1 << rnd;
        bool act = (c < 8) && ((c & (2 * step - 1)) == 0);
        float N2[R][R];
        if (act) {
            float A[R][R], Bm[R][R];
#pragma unroll
            for (int ii = 0; ii < R; ++ii)
#pragma unroll
                for (int j = 0; j < R; ++j) {
                    A[ii][j]  = gm[c + step][ii * 4 + j];
                    Bm[ii][j] = gm[c][ii * 4 + j];
                }
#pragma unroll
            for (int ii = 0; ii < R; ++ii)
#pragma unroll
                for (int j = 0; j < R; ++j)
                    N2[ii][j] = A[ii][0] * Bm[0][j] + A[ii][1] * Bm[1][j] +
                                A[ii][2] * Bm[2][j] + A[ii][3] * Bm[3][j];
        }
        __syncthreads();
        if (act) {
#pragma unroll
            for (int ii = 0; ii < R; ++ii)
#pragma unroll
                for (int j = 0; j < R; ++j) gm[c][ii * 4 + j] = N2[ii][j];
        }
        __syncthreads();
    }

    if (tid < 4)
        *(float4*)(bprod + ((size_t)(b * 8 + tc)) * 16 + tid * 4) =
            *(const float4*)(&gm[0][tid * 4]);
}

// ---------------------------------------------------------------------------
// K4: one block per batch, 64 threads. (R2 code, exact)
// ---------------------------------------------------------------------------
__global__ void k_chain(const float* __restrict__ bprod, const float* __restrict__ xbar,
                        const float* __restrict__ wa, const float* __restrict__ wb,
                        float* __restrict__ out) {
    __shared__ float mats[8][17];     // +1 pad
    __shared__ float abp[64];
    int b   = blockIdx.x;
    int tid = threadIdx.x;            // 0..63

    {
        int r   = tid & 3;
        int sel = (tid >> 2) & 1;
        int seg = tid >> 3;           // 0..7, 128 d each
        const float* w  = sel ? wb : wa;
        const float* xp = xbar + b * D;
        float s = 0.f;
#pragma unroll 8
        for (int d = seg * 128; d < seg * 128 + 128; ++d)
            s += xp[d] * w[d * R + r];
        abp[tid] = s;
    }

    if (tid < 32) {
        int c = tid >> 2, q = tid & 3;
        *(float4*)(&mats[c][q * 4]) =
            *(const float4*)(bprod + ((size_t)(b * 8 + c)) * 16 + q * 4);
    }
    __syncthreads();

    int c = tid;
    for (int rnd = 0; rnd < 3; ++rnd) {
        int step = 1 << rnd;
        bool act = (c < 8) && ((c & (2 * step - 1)) == 0);
        float N2[R][R];
        if (act) {
            float A[R][R], Bm[R][R];
#pragma unroll
            for (int i = 0; i < R; ++i)
#pragma unroll
                for (int j = 0; j < R; ++j) {
                    A[i][j]  = mats[c + step][i * 4 + j];
                    Bm[i][j] = mats[c][i * 4 + j];
                }
#pragma unroll
            for (int i = 0; i < R; ++i)
#pragma unroll
                for (int j = 0; j < R; ++j)
                    N2[i][j] = A[i][0] * Bm[0][j] + A[i][1] * Bm[1][j] +
                               A[i][2] * Bm[2][j] + A[i][3] * Bm[3][j];
        }
        __syncthreads();
        if (act) {
#pragma unroll
            for (int i = 0; i < R; ++i)
#pragma unroll
                for (int j = 0; j < R; ++j) mats[c][i * 4 + j] = N2[i][j];
        }
        __syncthreads();
    }

    if (tid == 0) {
        float a[R], be[R];
#pragma unroll
        for (int r = 0; r < R; ++r) {
            float sa = 0.f, sb = 0.f;
#pragma unroll
            for (int seg = 0; seg < 8; ++seg) {
                sa += abp[(seg << 3) | r];
                sb += abp[(seg << 3) | 4 | r];
            }
            a[r] = sa; be[r] = sb;
        }
        float sa = fabsf(a[0]) + fabsf(a[1]) + fabsf(a[2]) + fabsf(a[3]);
        float v0[R];
#pragma unroll
        for (int r = 0; r < R; ++r) v0[r] = fabsf(a[r]) / sa;
        float v[R];
#pragma unroll
        for (int i = 0; i < R; ++i)
            v[i] = mats[0][i * 4 + 0] * v0[0] + mats[0][i * 4 + 1] * v0[1] +
                   mats[0][i * 4 + 2] * v0[2] + mats[0][i * 4 + 3] * v0[3];
        float sb = fabsf(be[0]) + fabsf(be[1]) + fabsf(be[2]) + fabsf(be[3]);
        float prob = (fabsf(be[0]) * v[0] + fabsf(be[1]) * v[1] +
                      fabsf(be[2]) * v[2] + fabsf(be[3]) * v[3]) / sb;
        atomicAdd(out, -logf(prob) * 0.125f);
    }
}

extern "C" void kernel_launch(void* const* d_in, const int* in_sizes, int n_in,
                              void* d_out, int out_size, void* d_ws, size_t ws_size,
                              hipStream_t stream) {
    const float* x      = (const float*)d_in[0];   // [8,512,1024] fp32
    const int*   labels = (const int*)d_in[1];     // [8,512] int32
    const float* wa     = (const float*)d_in[2];   // [1024,4]
    const float* wb     = (const float*)d_in[3];   // [1024,4]
    const float* wv     = (const float*)d_in[4];   // [1024,32768]
    float* out = (float*)d_out;                    // scalar loss

    float* xbar    = (float*)d_ws;                           // 8192 floats
    float* partial = xbar + Bq * D;                          // 8*32*1024 = 1 MiB
    float* part    = partial + (size_t)Bq * NTC * D;         // 16*8*32768 = 16 MiB
    float* bprod   = part + (size_t)DSPLIT * Bq * NCOL;      // 8*8*16 floats

    k_xbar<<<dim3(Bq, NTC), 256, 0, stream>>>(x, partial, out);
    k_xred<<<32, 256, 0, stream>>>(partial, xbar);
    k_core<<<dim3(NCOL / CBLK, DSPLIT), 256, 0, stream>>>(wv, xbar, part);
    k_gather<<<dim3(Bq, 8), 256, 0, stream>>>(part, labels, bprod);
    k_chain<<<Bq, 64, 0, stream>>>(bprod, xbar, wa, wb, out);
}